// Round 8
// baseline (179.203 us; speedup 1.0000x reference)
//
#include <hip/hip_runtime.h>
#include <hip/hip_bf16.h>
#include <cstdint>

// Problem constants (fixed by setup_inputs)
#define B_    32
#define T_    4096
#define C_    256
#define BM    64     // time rows per block
#define DMAX  16     // max supported dilation (problem uses 4)
#define NROWS (BM + DMAX)

typedef __attribute__((ext_vector_type(8))) short bf16x8;
typedef __attribute__((ext_vector_type(4))) float f32x4;
typedef __attribute__((ext_vector_type(4))) short s16x4;

static __device__ __forceinline__ short f2bf(float f) {
  __hip_bfloat16 h = __float2bfloat16(f);
  union { __hip_bfloat16 h; short s; } u; u.h = h;
  return u.s;
}

static __device__ __forceinline__ float rcp_(float x) {
  return __builtin_amdgcn_rcpf(x);
}

// ---------------------------------------------------------------------------
// Prep: bf16 weight image, LINEAR layout for direct per-lane fragment loads:
//   wimg[((nb*16 + ks)*256 + np)*32 + kk]   (shorts)
// nb = N-half, ks = k-step (K=32), np = local col (0..127 value, 128..255
// gate), kk = k within step. k = 32*ks + kk: k<256 -> tap0, else tap1.
// ---------------------------------------------------------------------------
__global__ void prep_weights(const float* __restrict__ Wv, const float* __restrict__ Wg,
                             const float* __restrict__ bv, const float* __restrict__ bg,
                             short* __restrict__ wimg, float* __restrict__ bcat) {
  int id = blockIdx.x * 256 + threadIdx.x;   // 2*16*256*32 = 262144 total
  int kk = id & 31;
  int np = (id >> 5) & 255;
  int ks = (id >> 13) & 15;
  int nb = id >> 17;
  int k = ks * 32 + kk, tap = k >> 8, kr = k & 255;
  int sel = np >> 7;
  int f = nb * 128 + (np & 127);
  const float* W = sel ? Wg : Wv;
  wimg[id] = f2bf(W[((size_t)tap * 256 + kr) * 256 + f]);
  if (id < 512) bcat[id] = (id < 256) ? bv[id] : bg[id - 256];
}

// ---------------------------------------------------------------------------
// Main: 512 threads = 8 waves (2 wm x 4 wn). Block = 64 time rows x FULL
// N=512 (merged halves: x staged ONCE per tile). Wave (wm,wn): rows
// [32wm,+32), value cols [64wn,+64), gate cols [256+64wn,+64) -> v/g pairs
// share a lane. LDS = 40 KiB x-tile only -> 2 blocks/CU, 16 waves/CU.
// K-loop BARRIER-FREE; weights straight from L2 to VGPRs. Transposed MFMA
// (weights in A-slot) -> float4 nt-stores.
// ---------------------------------------------------------------------------
__global__ __launch_bounds__(512, 4) void snail_main(
    const float* __restrict__ x, const short* __restrict__ wimg,
    const float* __restrict__ bcat, const int* __restrict__ dptr,
    float* __restrict__ out) {
  __shared__ __align__(16) short lx[NROWS * C_];   // 40 KiB, swizzled bf16 x-tile

  const int d = *dptr;
  // XCD-aware bijective swizzle (2048 blocks, 2048 % 8 == 0)
  const int bid = blockIdx.x;
  const int swz = (bid & 7) * 256 + (bid >> 3);
  const int t0 = (swz & 63) * BM;  // time tile
  const int b  = swz >> 6;         // batch

  const int tid  = threadIdx.x;
  const int lane = tid & 63;
  const int w    = tid >> 6;
  const int wm   = w >> 2;         // 0..1: row half
  const int wn   = w & 3;          // 0..3: col quarter
  const int row15 = lane & 15;
  const int qw    = lane >> 4;

  const float* xb = x + (size_t)b * T_ * C_;
  float* ob = out + (size_t)b * T_ * 512;

  // ---- stage x rows t0-d..t0+BM-1 into LDS (bf16, swizzled); fuse the exact
  //      fp32 passthrough (full 256-col half, contiguous per row).
  const int nrows = BM + d;
  for (int i = tid; i < nrows * 64; i += 512) {
    int r = i >> 6, c4 = i & 63;
    int t = t0 - d + r;
    f32x4 v = (f32x4){0.f, 0.f, 0.f, 0.f};
    if (t >= 0) v = *(const f32x4*)(xb + (size_t)t * C_ + c4 * 4);
    if (r >= d)
      __builtin_nontemporal_store(v, (f32x4*)(ob + (size_t)t * 512 + C_ + c4 * 4));
    s16x4 s;
    s.x = f2bf(v.x); s.y = f2bf(v.y); s.z = f2bf(v.z); s.w = f2bf(v.w);
    int byte = (r * 512 + c4 * 8) ^ ((r & 7) << 4);
    *(s16x4*)((char*)lx + byte) = s;
  }
  __syncthreads();   // the ONLY barrier

  f32x4 accv[2][4], accg[2][4];
#pragma unroll
  for (int mi = 0; mi < 2; ++mi)
#pragma unroll
    for (int ni = 0; ni < 4; ++ni) {
      accv[mi][ni] = (f32x4){0.f, 0.f, 0.f, 0.f};
      accg[mi][ni] = (f32x4){0.f, 0.f, 0.f, 0.f};
    }

  // per-lane weight base: nb_w = wn>>1, np_value = (wn&1)*64 + row15, kk = qw*8
  const short* wl = wimg + (size_t)(wn >> 1) * 131072 +
                    ((wn & 1) * 64 + row15) * 32 + qw * 8;

#pragma unroll 2
  for (int ks = 0; ks < 16; ++ks) {
    const short* wk = wl + ks * 8192;
    bf16x8 wv_[4], wg_[4];
#pragma unroll
    for (int ni = 0; ni < 4; ++ni) {
      wv_[ni] = *(const bf16x8*)(wk + ni * 512);          // value cols
      wg_[ni] = *(const bf16x8*)(wk + ni * 512 + 4096);   // gate cols (+128 np)
    }

    // A fragments (x): lane holds A[row=32wm+16mi+row15+rofs][k=qw*8+j]
    bf16x8 af[2];
    const int rofs = (ks >= 8) ? d : 0;
    const int cb = (ks & 7) * 64 + qw * 16;
#pragma unroll
    for (int mi = 0; mi < 2; ++mi) {
      int r = 32 * wm + 16 * mi + row15 + rofs;
      af[mi] = *(const bf16x8*)((const char*)lx + ((r * 512 + cb) ^ ((r & 7) << 4)));
    }
#pragma unroll
    for (int ni = 0; ni < 4; ++ni)
#pragma unroll
      for (int mi = 0; mi < 2; ++mi) {
        // TRANSPOSED: weights in A-slot -> D[f][t]; lane holds 4 consecutive f
        accv[mi][ni] = __builtin_amdgcn_mfma_f32_16x16x32_bf16(wv_[ni], af[mi], accv[mi][ni], 0, 0, 0);
        accg[mi][ni] = __builtin_amdgcn_mfma_f32_16x16x32_bf16(wg_[ni], af[mi], accg[mi][ni], 0, 0, 0);
      }
  }

  // ---- epilogue: out[t][f] = tanh(v+bv)*sigmoid(g+bg), float4 nt-stores
  //      D^T layout: t = t0+32wm+16mi+row15 ; f = 64wn + 16ni + qw*4 + j
#pragma unroll
  for (int ni = 0; ni < 4; ++ni) {
    int f0 = 64 * wn + 16 * ni + qw * 4;
    f32x4 bv4 = *(const f32x4*)(bcat + f0);
    f32x4 bg4 = *(const f32x4*)(bcat + 256 + f0);
#pragma unroll
    for (int mi = 0; mi < 2; ++mi) {
      int t = t0 + 32 * wm + 16 * mi + row15;
      f32x4 v = accv[mi][ni], g = accg[mi][ni];
      f32x4 res;
#pragma unroll
      for (int j = 0; j < 4; ++j) {
        float vv = v[j] + bv4[j], gg = g[j] + bg4[j];
        float th = 1.f - 2.f * rcp_(__expf(2.f * vv) + 1.f);
        float sg = rcp_(1.f + __expf(-gg));
        res[j] = th * sg;
      }
      __builtin_nontemporal_store(res, (f32x4*)(ob + (size_t)t * 512 + f0));
    }
  }
}

extern "C" void kernel_launch(void* const* d_in, const int* in_sizes, int n_in,
                              void* d_out, int out_size, void* d_ws, size_t ws_size,
                              hipStream_t stream) {
  const float* x  = (const float*)d_in[0];
  const float* Wv = (const float*)d_in[1];
  const float* bv = (const float*)d_in[2];
  const float* Wg = (const float*)d_in[3];
  const float* bg = (const float*)d_in[4];
  const int* dil  = (const int*)d_in[5];
  float* out = (float*)d_out;

  short* wimg = (short*)d_ws;                          // 512 KiB weight image
  float* bcat = (float*)((char*)d_ws + 16 * 32768);    // 2 KiB biases

  prep_weights<<<1024, 256, 0, stream>>>(Wv, Wg, bv, bg, wimg, bcat);
  snail_main<<<B_ * (T_ / BM), 512, 0, stream>>>(x, wimg, bcat, dil, out);
}

// Round 9
// 110.356 us; speedup vs baseline: 1.6239x; 1.6239x over previous
//
#include <hip/hip_runtime.h>
#include <hip/hip_bf16.h>
#include <cstdint>

// Problem constants (fixed by setup_inputs)
#define B_    32
#define T_    4096
#define C_    256
#define BM    64     // time rows per block
#define DMAX  16     // max supported dilation (problem uses 4)
#define NROWS (BM + DMAX)

typedef __attribute__((ext_vector_type(8))) short bf16x8;
typedef __attribute__((ext_vector_type(4))) float f32x4;
typedef __attribute__((ext_vector_type(4))) short s16x4;

static __device__ __forceinline__ short f2bf(float f) {
  __hip_bfloat16 h = __float2bfloat16(f);
  union { __hip_bfloat16 h; short s; } u; u.h = h;
  return u.s;
}

static __device__ __forceinline__ float rcp_(float x) {
  return __builtin_amdgcn_rcpf(x);
}

// ---------------------------------------------------------------------------
// Prep: bf16 weight image, LINEAR layout for direct per-lane fragment loads:
//   wimg[((nb*16 + ks)*256 + np)*32 + kk]   (shorts)
// nb = N-half, ks = k-step (K=32), np = local col (0..127 value, 128..255
// gate), kk = k within step. k = 32*ks + kk: k<256 -> tap0, else tap1.
// ---------------------------------------------------------------------------
__global__ void prep_weights(const float* __restrict__ Wv, const float* __restrict__ Wg,
                             const float* __restrict__ bv, const float* __restrict__ bg,
                             short* __restrict__ wimg, float* __restrict__ bcat) {
  int id = blockIdx.x * 256 + threadIdx.x;   // 2*16*256*32 = 262144 total
  int kk = id & 31;
  int np = (id >> 5) & 255;
  int ks = (id >> 13) & 15;
  int nb = id >> 17;
  int k = ks * 32 + kk, tap = k >> 8, kr = k & 255;
  int sel = np >> 7;
  int f = nb * 128 + (np & 127);
  const float* W = sel ? Wg : Wv;
  wimg[id] = f2bf(W[((size_t)tap * 256 + kr) * 256 + f]);
  if (id < 512) bcat[id] = (id < 256) ? bv[id] : bg[id - 256];
}

// ---------------------------------------------------------------------------
// Main: 512 threads = 8 waves, 1x8 N-partition (NO weight duplication:
// wave w -> nb = w>>2, covers value np [32(w&3),+32) and gate np +128; per
// k-step each wave does 4x 1KB coalesced weight loads + 16 MFMAs — identical
// per-wave structure to the round-6 winner, but x is staged ONCE per tile
// (was twice). LDS = 40 KiB x-tile only. K-loop BARRIER-FREE with register
// ping-pong weight prefetch. Transposed MFMA -> float4 nt-stores.
// ---------------------------------------------------------------------------
__global__ __launch_bounds__(512, 4) void snail_main(
    const float* __restrict__ x, const short* __restrict__ wimg,
    const float* __restrict__ bcat, const int* __restrict__ dptr,
    float* __restrict__ out) {
  __shared__ __align__(16) short lx[NROWS * C_];   // 40 KiB, swizzled bf16 x-tile

  const int d = *dptr;
  // XCD-aware bijective swizzle (2048 blocks, 2048 % 8 == 0)
  const int bid = blockIdx.x;
  const int swz = (bid & 7) * 256 + (bid >> 3);
  const int t0 = (swz & 63) * BM;  // time tile
  const int b  = swz >> 6;         // batch

  const int tid  = threadIdx.x;
  const int lane = tid & 63;
  const int w    = tid >> 6;
  const int nb   = w >> 2;         // N-half owned by this wave
  const int wq   = w & 3;          // quarter within the half
  const int row15 = lane & 15;
  const int qw    = lane >> 4;

  const float* xb = x + (size_t)b * T_ * C_;
  float* ob = out + (size_t)b * T_ * 512;

  // ---- stage x rows t0-d..t0+BM-1 into LDS (bf16, swizzled) once per tile;
  //      fuse the exact fp32 passthrough (full rows, contiguous).
  for (int i = tid; i < d * 64; i += 512) {          // prefix rows [0,d)
    int r = i >> 6, c4 = i & 63;
    int t = t0 - d + r;
    f32x4 v = (f32x4){0.f, 0.f, 0.f, 0.f};
    if (t >= 0) v = *(const f32x4*)(xb + (size_t)t * C_ + c4 * 4);
    s16x4 s;
    s.x = f2bf(v.x); s.y = f2bf(v.y); s.z = f2bf(v.z); s.w = f2bf(v.w);
    int byte = (r * 512 + c4 * 8) ^ ((r & 7) << 4);
    *(s16x4*)((char*)lx + byte) = s;
  }
#pragma unroll 4
  for (int ii = 0; ii < 8; ++ii) {                   // main rows [d, d+BM)
    int i = ii * 512 + tid;
    int rr = i >> 6, c4 = i & 63;
    int t = t0 + rr, r = rr + d;
    f32x4 v = *(const f32x4*)(xb + (size_t)t * C_ + c4 * 4);
    __builtin_nontemporal_store(v, (f32x4*)(ob + (size_t)t * 512 + C_ + c4 * 4));
    s16x4 s;
    s.x = f2bf(v.x); s.y = f2bf(v.y); s.z = f2bf(v.z); s.w = f2bf(v.w);
    int byte = (r * 512 + c4 * 8) ^ ((r & 7) << 4);
    *(s16x4*)((char*)lx + byte) = s;
  }
  __syncthreads();   // the ONLY barrier

  f32x4 accv[4][2], accg[4][2];
#pragma unroll
  for (int mi = 0; mi < 4; ++mi)
#pragma unroll
    for (int ni = 0; ni < 2; ++ni) {
      accv[mi][ni] = (f32x4){0.f, 0.f, 0.f, 0.f};
      accg[mi][ni] = (f32x4){0.f, 0.f, 0.f, 0.f};
    }

  // per-lane weight base: np = wq*32 + row15 (value), kk = qw*8
  const short* wl = wimg + (size_t)nb * 131072 + (wq * 32 + row15) * 32 + qw * 8;

#define LOADW(D0, D1, D2, D3, KS) do {                                  \
    const short* wk_ = wl + (KS) * 8192;                                \
    D0 = *(const bf16x8*)(wk_);                                         \
    D1 = *(const bf16x8*)(wk_ + 512);                                   \
    D2 = *(const bf16x8*)(wk_ + 4096);                                  \
    D3 = *(const bf16x8*)(wk_ + 4608);                                  \
  } while (0)

#define STEP(B0, B1, G0, G1, KS) do {                                   \
    bf16x8 af[4];                                                       \
    const int rofs_ = ((KS) >= 8) ? d : 0;                              \
    const int cb_ = ((KS) & 7) * 64 + qw * 16;                          \
    _Pragma("unroll")                                                   \
    for (int mi = 0; mi < 4; ++mi) {                                    \
      int r_ = 16 * mi + row15 + rofs_;                                 \
      af[mi] = *(const bf16x8*)((const char*)lx +                       \
               ((r_ * 512 + cb_) ^ ((r_ & 7) << 4)));                   \
    }                                                                   \
    _Pragma("unroll")                                                   \
    for (int mi = 0; mi < 4; ++mi) {                                    \
      accv[mi][0] = __builtin_amdgcn_mfma_f32_16x16x32_bf16(B0, af[mi], accv[mi][0], 0, 0, 0); \
      accv[mi][1] = __builtin_amdgcn_mfma_f32_16x16x32_bf16(B1, af[mi], accv[mi][1], 0, 0, 0); \
      accg[mi][0] = __builtin_amdgcn_mfma_f32_16x16x32_bf16(G0, af[mi], accg[mi][0], 0, 0, 0); \
      accg[mi][1] = __builtin_amdgcn_mfma_f32_16x16x32_bf16(G1, af[mi], accg[mi][1], 0, 0, 0); \
    }                                                                   \
  } while (0)

  bf16x8 a0, a1, a2, a3, b0, b1, b2, b3;
  LOADW(a0, a1, a2, a3, 0);
#pragma unroll 1
  for (int ks2 = 0; ks2 < 8; ++ks2) {
    LOADW(b0, b1, b2, b3, 2 * ks2 + 1);   // prefetch odd step
    STEP(a0, a1, a2, a3, 2 * ks2);        // compute even step (loads in flight)
    if (ks2 < 7) LOADW(a0, a1, a2, a3, 2 * ks2 + 2);  // prefetch next even
    STEP(b0, b1, b2, b3, 2 * ks2 + 1);    // compute odd step
  }
#undef LOADW
#undef STEP

  // ---- epilogue: out[t][f] = tanh(v+bv)*sigmoid(g+bg)
  //      = (e2v-1) * rcp((e2v+1)*(1+eng)), e2v=exp(2(v+bv)), eng=exp(-(g+bg))
  //      D^T layout: t = t0+16mi+row15 ; f = nb*128 + wq*32 + 16ni + qw*4 + j
#pragma unroll
  for (int ni = 0; ni < 2; ++ni) {
    int f0 = nb * 128 + wq * 32 + 16 * ni + qw * 4;
    f32x4 bv4 = *(const f32x4*)(bcat + f0);
    f32x4 bg4 = *(const f32x4*)(bcat + 256 + f0);
    f32x4 bv2 = bv4 + bv4;     // 2*bias_v
    f32x4 bgn = -bg4;          // -bias_g
#pragma unroll
    for (int mi = 0; mi < 4; ++mi) {
      int t = t0 + 16 * mi + row15;
      f32x4 v = accv[mi][ni], g = accg[mi][ni];
      f32x4 res;
#pragma unroll
      for (int j = 0; j < 4; ++j) {
        float e2v = __expf(__builtin_fmaf(v[j], 2.f, bv2[j]));
        float eng = __expf(__builtin_fmaf(g[j], -1.f, bgn[j]));
        res[j] = (e2v - 1.f) * rcp_((e2v + 1.f) * (1.f + eng));
      }
      __builtin_nontemporal_store(res, (f32x4*)(ob + (size_t)t * 512 + f0));
    }
  }
}

extern "C" void kernel_launch(void* const* d_in, const int* in_sizes, int n_in,
                              void* d_out, int out_size, void* d_ws, size_t ws_size,
                              hipStream_t stream) {
  const float* x  = (const float*)d_in[0];
  const float* Wv = (const float*)d_in[1];
  const float* bv = (const float*)d_in[2];
  const float* Wg = (const float*)d_in[3];
  const float* bg = (const float*)d_in[4];
  const int* dil  = (const int*)d_in[5];
  float* out = (float*)d_out;

  short* wimg = (short*)d_ws;                          // 512 KiB weight image
  float* bcat = (float*)((char*)d_ws + 16 * 32768);    // 2 KiB biases

  prep_weights<<<1024, 256, 0, stream>>>(Wv, Wg, bv, bg, wimg, bcat);
  snail_main<<<B_ * (T_ / BM), 512, 0, stream>>>(x, wimg, bcat, dil, out);
}